// Round 19
// baseline (167.136 us; speedup 1.0000x reference)
//
#include <hip/hip_runtime.h>
#include <stdint.h>

#define DEVFN __device__ __forceinline__

using f32x4   = __attribute__((ext_vector_type(4)))  float;
using f32x8   = __attribute__((ext_vector_type(8)))  float;
using f32x16  = __attribute__((ext_vector_type(16))) float;
using us4     = __attribute__((ext_vector_type(4)))  unsigned short;
using us8     = __attribute__((ext_vector_type(8)))  unsigned short;
using u32x4   = __attribute__((ext_vector_type(4)))  unsigned int;
using bf16x8  = __attribute__((ext_vector_type(8)))  __bf16;

DEVFN unsigned short f2b(float x){
    union { float f; unsigned u; } v; v.f = x;
    unsigned r = v.u + 0x7FFFu + ((v.u >> 16) & 1u);   // RNE
    return (unsigned short)(r >> 16);
}
DEVFN float b2f(unsigned short u){
    union { unsigned u; float f; } v; v.u = ((unsigned)u) << 16; return v.f;
}
DEVFN bf16x8 ld_bf16x8(const unsigned short* p){
    return __builtin_bit_cast(bf16x8, *(const us8*)p);
}
DEVFN bf16x8 pack_bf16x8v(f32x8 f){
    us8 u;
#pragma unroll
    for (int j = 0; j < 8; ++j) u[j] = f2b(f[j]);
    return __builtin_bit_cast(bf16x8, u);
}
DEVFN f32x16 zero16(){
    f32x16 z;
#pragma unroll
    for (int i = 0; i < 16; ++i) z[i] = 0.f;
    return z;
}
DEVFN f32x16 mfma_bf16(bf16x8 a, bf16x8 b, f32x16 c){
    return __builtin_amdgcn_mfma_f32_32x32x16_bf16(a, b, c, 0, 0, 0);
}
// SROA-safe strided A-load: 8 channel values for this lane's pixel, by value.
template<int HW>
DEVFN f32x8 loadA8(const float* ap){
    f32x8 v;
#pragma unroll
    for (int j = 0; j < 8; ++j) v[j] = ap[(size_t)j * HW];
    return v;
}

// ---------------- prep: pack all weights into MFMA B-fragment order ----------------
// frag[((ks*NT + nt)*64 + lane)*8 + j] = W[ks*16 + (lane>>5)*8 + j][nt*32 + (lane&31)]
__global__ __launch_bounds__(256) void k_prep(
        const float* __restrict__ w0, const float* __restrict__ w1,
        const float* __restrict__ w2, const float* __restrict__ qw,
        const float* __restrict__ pw, const float* __restrict__ kw,
        const float* __restrict__ vw,
        unsigned short* __restrict__ o0, unsigned short* __restrict__ o1,
        unsigned short* __restrict__ o2, unsigned short* __restrict__ oq,
        unsigned short* __restrict__ op, unsigned short* __restrict__ ok,
        unsigned short* __restrict__ ov){
    int gid = blockIdx.x * 256 + threadIdx.x;
    const float* in; unsigned short* out; int t, E;
    if (gid < 8192)       { in = w0; out = o0; t = gid;         E = 256; }
    else if (gid < 24576) { in = w1; out = o1; t = gid - 8192;  E = 256; }
    else if (gid < 57344) { in = w2; out = o2; t = gid - 24576; E = 256; }
    else if (gid < 73728) { in = qw; out = oq; t = gid - 57344; E = 256; }
    else if (gid < 90112) { in = pw; out = op; t = gid - 73728; E = 512; }
    else if (gid < 98304) { in = kw; out = ok; t = gid - 90112; E = 256; }
    else                  { in = vw; out = ov; t = gid - 98304; E = 256; }
    int lane = t & 63, fn = t >> 6;
    int nt, ks;
    if (E == 512){ nt = fn & 15; ks = fn >> 4; }
    else         { nt = fn & 7;  ks = fn >> 3; }
    int c0 = ks*16 + (lane >> 5)*8, e = nt*32 + (lane & 31);
    us8 u;
#pragma unroll
    for (int j = 0; j < 8; ++j) u[j] = f2b(in[(size_t)(c0 + j) * E + e]);
    *(us8*)(out + (size_t)t * 8) = u;
}

// ---------------- fused 1x1-conv + adaptive max pool -> xc[b][27][256] ----------------
// Barrier-free: wave-task = (scale, b, bin, e-quarter). acc[2] (2 n-tiles of 32 e).
// W frags read directly (L2/L3-resident, coalesced 1KB wave loads); A strided loads
// with explicit depth-2 rotating prefetch. Pool-max wave-private -> no races.
template<int C, int WIMG, int BINW, int NSUB>
DEVFN void conv_wave(const float* __restrict__ X, const unsigned short* __restrict__ WF,
                     const float* __restrict__ CB, float* __restrict__ xc,
                     int b, int bin, int eq, int sbase){
    const int HW = WIMG * WIMG;
    const int NK = C / 16;
    int lane = threadIdx.x & 63, lo = lane & 31, hi = lane >> 5;
    int binr = bin / 3, binc = bin % 3;
    const unsigned short* wf = WF + (size_t)lane * 8;   // + (ks*8 + nt)*512
    int nt0 = eq * 2, nt1 = eq * 2 + 1;
    float rmax0 = -3.4e38f, rmax1 = -3.4e38f;

    for (int sub = 0; sub < NSUB; ++sub){
        int prow, pcol;
        if constexpr (BINW == 16){ prow = sub*2 + (lo>>4); pcol = lo & 15; }
        else if constexpr (BINW == 8){ prow = sub*4 + (lo>>3); pcol = lo & 7; }
        else { prow = (lo & 15) >> 2; pcol = lo & 3; }   // 16 px duplicated x2
        int gr = binr * BINW + prow, gc = binc * BINW + pcol;
        const float* Xp = X + (size_t)b * C * HW + gr * WIMG + gc + (size_t)hi * 8 * HW;

        f32x16 a0 = zero16(), a1 = zero16();
        f32x8 aC = loadA8<HW>(Xp);
        f32x8 aN = loadA8<HW>(Xp + (size_t)16 * HW);
        for (int ks = 0; ks < NK; ++ks){
            f32x8 aF;
            if (ks + 2 < NK) aF = loadA8<HW>(Xp + (size_t)(ks + 2) * 16 * HW);
            bf16x8 B0 = ld_bf16x8(wf + (size_t)(ks*8 + nt0) * 512);
            bf16x8 B1 = ld_bf16x8(wf + (size_t)(ks*8 + nt1) * 512);
            bf16x8 A = pack_bf16x8v(aC);
            a0 = mfma_bf16(A, B0, a0);
            a1 = mfma_bf16(A, B1, a1);
            aC = aN;
            if (ks + 2 < NK) aN = aF;
        }
        float m0 = a0[0], m1 = a1[0];
#pragma unroll
        for (int r = 1; r < 16; ++r){ m0 = fmaxf(m0, a0[r]); m1 = fmaxf(m1, a1[r]); }
        rmax0 = fmaxf(rmax0, m0);
        rmax1 = fmaxf(rmax1, m1);
    }
    rmax0 = fmaxf(rmax0, __shfl_xor(rmax0, 32));
    rmax1 = fmaxf(rmax1, __shfl_xor(rmax1, 32));
    if (hi == 0){
        size_t base = ((size_t)b * 27 + sbase + bin) * 256;
        int e0 = nt0 * 32 + lo, e1 = nt1 * 32 + lo;
        xc[base + e0] = rmax0 + CB[e0];
        xc[base + e1] = rmax1 + CB[e1];
    }
}

// 864 blocks x 256 thr = 3456 wave-tasks; longest (s0, 128 ksteps) dispatched first.
__global__ __launch_bounds__(256, 4) void k_conv_pool(
        const float* __restrict__ x0, const float* __restrict__ x1, const float* __restrict__ x2,
        const unsigned short* __restrict__ wt0, const unsigned short* __restrict__ wt1,
        const unsigned short* __restrict__ wt2,
        const float* __restrict__ cb0, const float* __restrict__ cb1, const float* __restrict__ cb2,
        float* __restrict__ xc){
    int task = blockIdx.x * 4 + (threadIdx.x >> 6);
    if (task < 1152){
        int r = task; int eq = r & 3; r >>= 2; int bin = r % 9, b = r / 9;
        conv_wave<256, 48, 16, 8>(x0, wt0, cb0, xc, b, bin, eq, 0);
    } else if (task < 2304){
        int r = task - 1152; int eq = r & 3; r >>= 2; int bin = r % 9, b = r / 9;
        conv_wave<512, 24, 8, 2>(x1, wt1, cb1, xc, b, bin, eq, 9);
    } else {
        int r = task - 2304; int eq = r & 3; r >>= 2; int bin = r % 9, b = r / 9;
        conv_wave<1024, 12, 4, 1>(x2, wt2, cb2, xc, b, bin, eq, 18);
    }
}

// ---------------- fused LN(text) + q-GEMM: q = LN(text) @ q_w + q_b -> bf16 ----------------
__global__ __launch_bounds__(128) void k_lnq(const float* __restrict__ text,
        const float* __restrict__ g, const float* __restrict__ bb,
        const unsigned short* __restrict__ qwt, const float* __restrict__ qb,
        unsigned short* __restrict__ qout){
    __shared__ unsigned short alds[32][520];
    int w = threadIdx.x >> 6, lane = threadIdx.x & 63, lo = lane & 31, hi = lane >> 5;
    size_t row0 = (size_t)blockIdx.x * 32;

    const float* gp = g  + lane * 8;
    const float* bp = bb + lane * 8;
    f32x4 g0 = *(const f32x4*)gp, g1 = *(const f32x4*)(gp+4);
    f32x4 b0 = *(const f32x4*)bp, b1 = *(const f32x4*)(bp+4);
#pragma unroll
    for (int it = 0; it < 16; ++it){
        int r = it * 2 + w;
        const float* p = text + (row0 + r) * 512 + lane * 8;
        f32x4 a = *(const f32x4*)p;
        f32x4 c = *(const f32x4*)(p + 4);
        float s = a[0]+a[1]+a[2]+a[3]+c[0]+c[1]+c[2]+c[3];
#pragma unroll
        for (int off = 32; off; off >>= 1) s += __shfl_xor(s, off);
        float mean = s * (1.f/512.f);
        float d[8];
        d[0]=a[0]-mean; d[1]=a[1]-mean; d[2]=a[2]-mean; d[3]=a[3]-mean;
        d[4]=c[0]-mean; d[5]=c[1]-mean; d[6]=c[2]-mean; d[7]=c[3]-mean;
        float vs = d[0]*d[0]+d[1]*d[1]+d[2]*d[2]+d[3]*d[3]+d[4]*d[4]+d[5]*d[5]+d[6]*d[6]+d[7]*d[7];
#pragma unroll
        for (int off = 32; off; off >>= 1) vs += __shfl_xor(vs, off);
        float rstd = rsqrtf(vs * (1.f/512.f) + 1e-5f);
        us8 o;
#pragma unroll
        for (int j = 0; j < 4; ++j) o[j]   = f2b(d[j]  *rstd*g0[j] + b0[j]);
#pragma unroll
        for (int j = 0; j < 4; ++j) o[4+j] = f2b(d[4+j]*rstd*g1[j] + b1[j]);
        *(us8*)(&alds[r][lane * 8]) = o;
    }
    __syncthreads();

    f32x16 acc[4];
#pragma unroll
    for (int i = 0; i < 4; ++i) acc[i] = zero16();
    const unsigned short* wf = qwt + (size_t)lane * 8;
    for (int ks = 0; ks < 32; ++ks){
        bf16x8 a = ld_bf16x8(&alds[lo][ks*16 + hi*8]);
#pragma unroll
        for (int i = 0; i < 4; ++i){
            int nt = w*4 + i;
            bf16x8 bfr = ld_bf16x8(wf + (size_t)(ks*8 + nt) * 512);
            acc[i] = mfma_bf16(a, bfr, acc[i]);
        }
    }
#pragma unroll
    for (int i = 0; i < 4; ++i){
        int e = (w*4 + i) * 32 + lo;
        float qbias = qb[e];
#pragma unroll
        for (int r = 0; r < 16; ++r){
            size_t row = row0 + (r & 3) + 8 * (r >> 2) + 4 * hi;
            qout[row * 256 + e] = f2b(acc[i][r] + qbias);
        }
    }
}

// ---------------- fused LN(xc) + K/V GEMM (MFMA) ----------------
__global__ __launch_bounds__(256) void k_kv(const float* __restrict__ xc,
        const float* __restrict__ kg, const float* __restrict__ kb,
        const float* __restrict__ vg, const float* __restrict__ vb,
        const unsigned short* __restrict__ kwt, const unsigned short* __restrict__ vwt,
        const float* __restrict__ k_bias, const float* __restrict__ v_bias,
        float* __restrict__ kout, float* __restrict__ vout){
    __shared__ unsigned short lnk[32][264];
    __shared__ unsigned short lnv[32][264];
    int w = threadIdx.x >> 6, lane = threadIdx.x & 63, lo = lane & 31, hi = lane >> 5;
    size_t row0 = (size_t)blockIdx.x * 32;
    int c0 = lane * 4;
    f32x4 kgv = *(const f32x4*)(kg + c0), kbv = *(const f32x4*)(kb + c0);
    f32x4 vgv = *(const f32x4*)(vg + c0), vbv = *(const f32x4*)(vb + c0);
#pragma unroll
    for (int rr = 0; rr < 8; ++rr){
        int r = w * 8 + rr;
        f32x4 xv = *(const f32x4*)(xc + (row0 + r) * 256 + c0);
        float s = xv[0]+xv[1]+xv[2]+xv[3];
#pragma unroll
        for (int off = 32; off; off >>= 1) s += __shfl_xor(s, off);
        float mean = s * (1.f/256.f);
        float d0 = xv[0]-mean, d1 = xv[1]-mean, d2 = xv[2]-mean, d3 = xv[3]-mean;
        float vs = d0*d0 + d1*d1 + d2*d2 + d3*d3;
#pragma unroll
        for (int off = 32; off; off >>= 1) vs += __shfl_xor(vs, off);
        float rstd = rsqrtf(vs * (1.f/256.f) + 1e-5f);
        us4 uk, uv;
        uk[0] = f2b(d0*rstd*kgv[0] + kbv[0]); uv[0] = f2b(d0*rstd*vgv[0] + vbv[0]);
        uk[1] = f2b(d1*rstd*kgv[1] + kbv[1]); uv[1] = f2b(d1*rstd*vgv[1] + vbv[1]);
        uk[2] = f2b(d2*rstd*kgv[2] + kbv[2]); uv[2] = f2b(d2*rstd*vgv[2] + vbv[2]);
        uk[3] = f2b(d3*rstd*kgv[3] + kbv[3]); uv[3] = f2b(d3*rstd*vgv[3] + vbv[3]);
        *(us4*)(&lnk[r][c0]) = uk;
        *(us4*)(&lnv[r][c0]) = uv;
    }
    __syncthreads();

    f32x16 acc[4];
#pragma unroll
    for (int i = 0; i < 4; ++i) acc[i] = zero16();
    const unsigned short* lds = (w < 2) ? &lnk[0][0] : &lnv[0][0];
    const unsigned short* wf  = ((w < 2) ? kwt : vwt) + (size_t)lane * 8;
    int ntb = (w & 1) * 4;
    for (int ks = 0; ks < 16; ++ks){
        bf16x8 a = ld_bf16x8(lds + lo*264 + ks*16 + hi*8);
#pragma unroll
        for (int i = 0; i < 4; ++i){
            int nt = ntb + i;
            bf16x8 bfr = ld_bf16x8(wf + (size_t)(ks*8 + nt) * 512);
            acc[i] = mfma_bf16(a, bfr, acc[i]);
        }
    }
    const float* bias = (w < 2) ? k_bias : v_bias;
    float* outp = (w < 2) ? kout : vout;
#pragma unroll
    for (int i = 0; i < 4; ++i){
        int e = (ntb + i) * 32 + lo;
        float bv = bias[e];
#pragma unroll
        for (int r = 0; r < 16; ++r){
            size_t row = row0 + (r & 3) + 8 * (r >> 2) + 4 * hi;
            outp[row * 256 + e] = acc[i][r] + bv;
        }
    }
}

// ---------------- fused MFMA attention + out-proj (+bias +text residual) ----------------
__global__ __launch_bounds__(256, 3) void k_attnproj(const unsigned short* __restrict__ qbf,
        const float* __restrict__ kbuf, const float* __restrict__ vbuf,
        const unsigned short* __restrict__ pwt, const float* __restrict__ pb,
        const float* __restrict__ text, float* __restrict__ out){
    int b = blockIdx.x >> 4;
    int rg = blockIdx.x & 15;
    __shared__ unsigned short klds[32][264];
    __shared__ unsigned short vT[256][36];
    __shared__ unsigned short qolds[32][264];
    int tid = threadIdx.x;
    int w = tid >> 6, lane = tid & 63, lo = lane & 31, hi = lane >> 5;
    size_t grow0 = (size_t)b * 512 + rg * 32;

    // ---- stage K (bf16, rows 27..31 zero), V^T (bf16, k 27..35 zero), Q ----
    for (int i = tid; i < 27 * 64; i += 256){
        int row = i >> 6, c4 = (i & 63) << 2;
        f32x4 kv = *(const f32x4*)(kbuf + ((size_t)b*27 + row) * 256 + c4);
        us4 u; u[0]=f2b(kv[0]); u[1]=f2b(kv[1]); u[2]=f2b(kv[2]); u[3]=f2b(kv[3]);
        *(us4*)(&klds[row][c4]) = u;
    }
    for (int i = tid; i < 330; i += 256){
        int row = 27 + i / 66, c4 = (i % 66) * 4;
        us4 z = {0,0,0,0};
        *(us4*)(&klds[row][c4]) = z;
    }
    {
        int ch = tid;
        for (int k = 0; k < 27; ++k)
            vT[ch][k] = f2b(vbuf[((size_t)b*27 + k) * 256 + ch]);
#pragma unroll
        for (int k = 27; k < 36; ++k) vT[ch][k] = 0;
    }
    for (int i = tid; i < 1024; i += 256){
        int row = i >> 5, c8 = (i & 31) << 3;
        *(us8*)(&qolds[row][c8]) = *(const us8*)(qbf + (grow0 + row) * 256 + c8);
    }
    __syncthreads();

    // ---- attention: wave w handles heads w and w+4 ----
#pragma unroll
    for (int hh = 0; hh < 2; ++hh){
        int h = w + hh * 4;
        int hc = h * 32;
        f32x16 s = zero16();
        {
            bf16x8 A0 = ld_bf16x8(&klds[lo][hc + hi*8]);
            bf16x8 B0 = ld_bf16x8(&qolds[lo][hc + hi*8]);
            s = mfma_bf16(A0, B0, s);
            bf16x8 A1 = ld_bf16x8(&klds[lo][hc + 16 + hi*8]);
            bf16x8 B1 = ld_bf16x8(&qolds[lo][hc + 16 + hi*8]);
            s = mfma_bf16(A1, B1, s);
        }
        // per-lane softmax over k-regs (masked), + 1 shfl for partner half
        float mx = -3.4e38f;
#pragma unroll
        for (int r = 0; r < 16; ++r){
            bool valid = hi ? (r < 12) : (r != 15);
            if (valid) mx = fmaxf(mx, s[r]);
        }
        mx = fmaxf(mx, __shfl_xor(mx, 32));
        float p[16]; float sum = 0.f;
#pragma unroll
        for (int r = 0; r < 16; ++r){
            bool valid = hi ? (r < 12) : (r != 15);
            p[r] = valid ? __expf((s[r] - mx) * 0.17677669529663687f) : 0.f;
            sum += p[r];
        }
        sum += __shfl_xor(sum, 32);
        float inv = 1.f / sum;
        unsigned pd[8];
#pragma unroll
        for (int i = 0; i < 8; ++i)
            pd[i] = (unsigned)f2b(p[2*i]*inv) | ((unsigned)f2b(p[2*i+1]*inv) << 16);

        // PV: O^T = V^T . P  (2 k-steps; P-frag from regs + partner exchange)
        f32x16 o = zero16();
#pragma unroll
        for (int c = 0; c < 2; ++c){
            unsigned own0 = hi ? pd[4*c+2] : pd[4*c];
            unsigned own1 = hi ? pd[4*c+3] : pd[4*c+1];
            unsigned snd0 = hi ? pd[4*c]   : pd[4*c+2];
            unsigned snd1 = hi ? pd[4*c+1] : pd[4*c+3];
            unsigned rcv0 = (unsigned)__shfl_xor((int)snd0, 32);
            unsigned rcv1 = (unsigned)__shfl_xor((int)snd1, 32);
            u32x4 bd;
            bd[0] = hi ? rcv0 : own0;
            bd[1] = hi ? rcv1 : own1;
            bd[2] = hi ? own0 : rcv0;
            bd[3] = hi ? own1 : rcv1;
            bf16x8 B = __builtin_bit_cast(bf16x8, bd);
            bf16x8 A = ld_bf16x8(&vT[hc + lo][c*16 + hi*8]);
            o = mfma_bf16(A, B, o);
        }
        // write O to qolds: reg r -> ch = (r&3)+8*(r>>2)+4*hi
#pragma unroll
        for (int g = 0; g < 4; ++g){
            us4 u;
#pragma unroll
            for (int j = 0; j < 4; ++j) u[j] = f2b(o[g*4 + j]);
            *(us4*)(&qolds[lo][hc + g*8 + hi*4]) = u;
        }
    }
    __syncthreads();

    // ---- proj: out = O @ proj_w + proj_b + text ----
    f32x16 acc[4];
#pragma unroll
    for (int i = 0; i < 4; ++i) acc[i] = zero16();
    const unsigned short* wf = pwt + (size_t)lane * 8;
    for (int ks = 0; ks < 16; ++ks){
        bf16x8 a = ld_bf16x8(&qolds[lo][ks*16 + hi*8]);
#pragma unroll
        for (int i = 0; i < 4; ++i){
            int nt = w*4 + i;
            bf16x8 bfr = ld_bf16x8(wf + (size_t)(ks*16 + nt) * 512);
            acc[i] = mfma_bf16(a, bfr, acc[i]);
        }
    }
#pragma unroll
    for (int i = 0; i < 4; ++i){
        int ct = (w*4 + i) * 32 + lo;
        float pbias = pb[ct];
#pragma unroll
        for (int r = 0; r < 16; ++r){
            size_t row = grow0 + (r & 3) + 8 * (r >> 2) + 4 * hi;
            out[row * 512 + ct] = acc[i][r] + pbias + text[row * 512 + ct];
        }
    }
}

extern "C" void kernel_launch(void* const* d_in, const int* in_sizes, int n_in,
                              void* d_out, int out_size, void* d_ws, size_t ws_size,
                              hipStream_t stream) {
    (void)in_sizes; (void)n_in; (void)out_size; (void)ws_size;
    const float* x0     = (const float*)d_in[0];
    const float* x1     = (const float*)d_in[1];
    const float* x2     = (const float*)d_in[2];
    const float* text   = (const float*)d_in[3];
    const float* w0     = (const float*)d_in[4];
    const float* cb0    = (const float*)d_in[5];
    const float* w1     = (const float*)d_in[6];
    const float* cb1    = (const float*)d_in[7];
    const float* w2     = (const float*)d_in[8];
    const float* cb2    = (const float*)d_in[9];
    const float* q_ln_g = (const float*)d_in[10];
    const float* q_ln_b = (const float*)d_in[11];
    const float* k_ln_g = (const float*)d_in[12];
    const float* k_ln_b = (const float*)d_in[13];
    const float* v_ln_g = (const float*)d_in[14];
    const float* v_ln_b = (const float*)d_in[15];
    const float* q_w    = (const float*)d_in[16];
    const float* q_b    = (const float*)d_in[17];
    const float* k_w    = (const float*)d_in[18];
    const float* k_b    = (const float*)d_in[19];
    const float* v_w    = (const float*)d_in[20];
    const float* v_b    = (const float*)d_in[21];
    const float* proj_w = (const float*)d_in[22];
    const float* proj_b = (const float*)d_in[23];
    float* out = (float*)d_out;

    char* wsb = (char*)d_ws; size_t off = 0;
    auto take = [&](size_t bytes) -> void* {
        void* p = wsb + off; off += (bytes + 255) & ~(size_t)255; return p;
    };
    unsigned short* qbf    = (unsigned short*)take((size_t)16384 * 256 * 2);
    float*          xc     = (float*)take((size_t)32 * 27 * 256 * 4);
    float*          kbuf   = (float*)take((size_t)32 * 27 * 256 * 4);
    float*          vbuf   = (float*)take((size_t)32 * 27 * 256 * 4);
    unsigned short* wt0    = (unsigned short*)take((size_t)256 * 256 * 2);
    unsigned short* wt1    = (unsigned short*)take((size_t)256 * 512 * 2);
    unsigned short* wt2    = (unsigned short*)take((size_t)256 * 1024 * 2);
    unsigned short* qwt    = (unsigned short*)take((size_t)256 * 512 * 2);
    unsigned short* pwt    = (unsigned short*)take((size_t)512 * 256 * 2);
    unsigned short* kwt    = (unsigned short*)take((size_t)256 * 256 * 2);
    unsigned short* vwt    = (unsigned short*)take((size_t)256 * 256 * 2);

    k_prep<<<416, 256, 0, stream>>>(w0, w1, w2, q_w, proj_w, k_w, v_w,
                                    wt0, wt1, wt2, qwt, pwt, kwt, vwt);
    k_conv_pool<<<864, 256, 0, stream>>>(x0, x1, x2, wt0, wt1, wt2, cb0, cb1, cb2, xc);
    k_lnq<<<512, 128, 0, stream>>>(text, q_ln_g, q_ln_b, qwt, q_b, qbf);
    k_kv<<<27, 256, 0, stream>>>(xc, k_ln_g, k_ln_b, v_ln_g, v_ln_b,
                                 kwt, vwt, k_b, v_b, kbuf, vbuf);
    k_attnproj<<<512, 256, 0, stream>>>(qbf, kbuf, vbuf, pwt, proj_b, text, out);
}

// Round 21
// 120.560 us; speedup vs baseline: 1.3863x; 1.3863x over previous
//
#include <hip/hip_runtime.h>
#include <stdint.h>

#define DEVFN __device__ __forceinline__

using f32x4   = __attribute__((ext_vector_type(4)))  float;
using f32x8   = __attribute__((ext_vector_type(8)))  float;
using f32x16  = __attribute__((ext_vector_type(16))) float;
using us4     = __attribute__((ext_vector_type(4)))  unsigned short;
using us8     = __attribute__((ext_vector_type(8)))  unsigned short;
using u32x4   = __attribute__((ext_vector_type(4)))  unsigned int;
using bf16x8  = __attribute__((ext_vector_type(8)))  __bf16;

DEVFN unsigned short f2b(float x){
    union { float f; unsigned u; } v; v.f = x;
    unsigned r = v.u + 0x7FFFu + ((v.u >> 16) & 1u);   // RNE
    return (unsigned short)(r >> 16);
}
DEVFN float b2f(unsigned short u){
    union { unsigned u; float f; } v; v.u = ((unsigned)u) << 16; return v.f;
}
DEVFN bf16x8 ld_bf16x8(const unsigned short* p){
    return __builtin_bit_cast(bf16x8, *(const us8*)p);
}
DEVFN bf16x8 pack_bf16x8v(f32x8 f){
    us8 u;
#pragma unroll
    for (int j = 0; j < 8; ++j) u[j] = f2b(f[j]);
    return __builtin_bit_cast(bf16x8, u);
}
DEVFN f32x16 zero16(){
    f32x16 z;
#pragma unroll
    for (int i = 0; i < 16; ++i) z[i] = 0.f;
    return z;
}
DEVFN f32x16 mfma_bf16(bf16x8 a, bf16x8 b, f32x16 c){
    return __builtin_amdgcn_mfma_f32_32x32x16_bf16(a, b, c, 0, 0, 0);
}
// async global->LDS, 16B per lane; LDS dest = wave-uniform base + lane*16
DEVFN void gload_lds16(const unsigned short* g, unsigned short* l){
    __builtin_amdgcn_global_load_lds(
        (const __attribute__((address_space(1))) unsigned int*)(const void*)g,
        (__attribute__((address_space(3))) unsigned int*)(void*)l,
        16, 0, 0);
}
// SROA-safe strided A-load: 8 channel values for this lane's pixel, by value.
template<int HW>
DEVFN f32x8 loadA8(const float* ap){
    f32x8 v;
#pragma unroll
    for (int j = 0; j < 8; ++j) v[j] = ap[(size_t)j * HW];
    return v;
}

// ---------------- prep: pack all weights into MFMA B-fragment order ----------------
__global__ __launch_bounds__(256) void k_prep(
        const float* __restrict__ w0, const float* __restrict__ w1,
        const float* __restrict__ w2, const float* __restrict__ qw,
        const float* __restrict__ pw, const float* __restrict__ kw,
        const float* __restrict__ vw,
        unsigned short* __restrict__ o0, unsigned short* __restrict__ o1,
        unsigned short* __restrict__ o2, unsigned short* __restrict__ oq,
        unsigned short* __restrict__ op, unsigned short* __restrict__ ok,
        unsigned short* __restrict__ ov){
    int gid = blockIdx.x * 256 + threadIdx.x;
    const float* in; unsigned short* out; int t, E;
    if (gid < 8192)       { in = w0; out = o0; t = gid;         E = 256; }
    else if (gid < 24576) { in = w1; out = o1; t = gid - 8192;  E = 256; }
    else if (gid < 57344) { in = w2; out = o2; t = gid - 24576; E = 256; }
    else if (gid < 73728) { in = qw; out = oq; t = gid - 57344; E = 256; }
    else if (gid < 90112) { in = pw; out = op; t = gid - 73728; E = 512; }
    else if (gid < 98304) { in = kw; out = ok; t = gid - 90112; E = 256; }
    else                  { in = vw; out = ov; t = gid - 98304; E = 256; }
    int lane = t & 63, fn = t >> 6;
    int nt, ks;
    if (E == 512){ nt = fn & 15; ks = fn >> 4; }
    else         { nt = fn & 7;  ks = fn >> 3; }
    int c0 = ks*16 + (lane >> 5)*8, e = nt*32 + (lane & 31);
    us8 u;
#pragma unroll
    for (int j = 0; j < 8; ++j) u[j] = f2b(in[(size_t)(c0 + j) * E + e]);
    *(us8*)(out + (size_t)t * 8) = u;
}

// ---------------- conv helpers (round-18 structure) ----------------
DEVFN void comp2(f32x16 (&acc)[4], f32x8 a, const unsigned short* bsmr, int kk, int ntb, int lane){
    bf16x8 A = pack_bf16x8v(a);
#pragma unroll
    for (int i = 0; i < 4; ++i){
        bf16x8 B = ld_bf16x8(bsmr + (kk*8 + ntb + i) * 512 + lane * 8);
        acc[i] = mfma_bf16(A, B, acc[i]);
    }
}

template<int C, int WIMG, int BINW>
DEVFN void conv_sub(const float* __restrict__ X, const unsigned short* __restrict__ WF,
                    unsigned short* bsm0, unsigned short* bsm1,
                    int b, int bin, int sub, int ntb, float* rmax){
    const int HW = WIMG * WIMG;
    const int NCH = C / 32;
    int w8 = threadIdx.x >> 6, lane = threadIdx.x & 63, lo = lane & 31, hi = lane >> 5;
    int binr = bin / 3, binc = bin % 3;
    int prow, pcol;
    if constexpr (BINW == 16){ prow = sub*2 + (lo>>4); pcol = lo & 15; }
    else if constexpr (BINW == 8){ prow = sub*4 + (lo>>3); pcol = lo & 7; }
    else { prow = (lo & 15) >> 2; pcol = lo & 3; }     // 16 px duplicated x2
    int gr = binr * BINW + prow, gc = binc * BINW + pcol;
    const float* Xk = X + (size_t)b * C * HW + gr * WIMG + gc + (size_t)hi * 8 * HW;

    f32x16 acc[4];
#pragma unroll
    for (int i = 0; i < 4; ++i) acc[i] = zero16();

    auto stage = [&](unsigned short* dst, int ch){
        const unsigned short* src = WF + (size_t)ch * 8192 + w8 * 1024 + lane * 8;
        unsigned short* dl = dst + w8 * 1024;
        gload_lds16(src,       dl);
        gload_lds16(src + 512, dl + 512);
    };

    __syncthreads();                  // prior readers of bsm done
    stage(bsm0, 0);
    f32x8 a0 = loadA8<HW>(Xk);
    f32x8 a1 = loadA8<HW>(Xk + (size_t)16 * HW);
    __syncthreads();                  // staging chunk0 + A0 complete

    unsigned short* cur = bsm0;
    unsigned short* nxt = bsm1;
    for (int c = 0; c < NCH; ++c){
        f32x8 p0, p1;
        bool more = (c + 1 < NCH);
        if (more){
            stage(nxt, c + 1);
            const float* Xn = Xk + (size_t)(c + 1) * 32 * HW;
            p0 = loadA8<HW>(Xn);
            p1 = loadA8<HW>(Xn + (size_t)16 * HW);
        }
        comp2(acc, a0, cur, 0, ntb, lane);
        comp2(acc, a1, cur, 1, ntb, lane);
        __syncthreads();              // drain stage(c+1)+A(c+1); cur free
        if (more){ a0 = p0; a1 = p1; }
        unsigned short* t = cur; cur = nxt; nxt = t;
    }
#pragma unroll
    for (int i = 0; i < 4; ++i){
        float m = acc[i][0];
#pragma unroll
        for (int r = 1; r < 16; ++r) m = fmaxf(m, acc[i][r]);
        rmax[i] = fmaxf(rmax[i], m);
    }
}

// ---------------- MERGED conv+pool (blk 0..543) and LN+q-GEMM (blk 544..1055) ----------------
// 512 threads. LDS union: conv = bsm0(16K)+bsm1(16K)+red(4K)=36KB; lnq = [32][520] = 33.3KB.
__global__ __launch_bounds__(512, 2) void k_convlnq(
        const float* __restrict__ x0, const float* __restrict__ x1, const float* __restrict__ x2,
        const unsigned short* __restrict__ wt0, const unsigned short* __restrict__ wt1,
        const unsigned short* __restrict__ wt2,
        const float* __restrict__ cb0, const float* __restrict__ cb1, const float* __restrict__ cb2,
        float* __restrict__ xc,
        const float* __restrict__ text, const float* __restrict__ qg,
        const float* __restrict__ qbb, const unsigned short* __restrict__ qwt,
        const float* __restrict__ qb, unsigned short* __restrict__ qout){
    __shared__ __attribute__((aligned(16))) char smem[36864];
    unsigned short* bsm0 = (unsigned short*)smem;
    unsigned short* bsm1 = (unsigned short*)(smem + 16384);
    float (*red)[4][32] = (float (*)[4][32])(smem + 32768);
    int blk = blockIdx.x, w = threadIdx.x >> 6, lane = threadIdx.x & 63;
    int lo = lane & 31, hi = lane >> 5;

    if (blk < 544){                       // ================= conv+pool =================
        int ntb = (w >> 2) * 4;           // e-half n-tile base
        float rmax[4];
#pragma unroll
        for (int i = 0; i < 4; ++i) rmax[i] = -3.4e38f;

        if (blk < 96){                    // ---- scale 2: bin = q*4 + (w&3)
            int b = blk / 3, q = blk % 3;
            int bin = q*4 + (w & 3);
            int bc = bin <= 8 ? bin : 8;
            conv_sub<1024, 12, 4>(x2, wt2, bsm0, bsm1, b, bc, 0, ntb, rmax);
#pragma unroll
            for (int i = 0; i < 4; ++i){
                float m = fmaxf(rmax[i], __shfl_xor(rmax[i], 32));
                if (hi == 0 && bin <= 8){
                    int e = (ntb + i)*32 + lo;
                    xc[((size_t)b*27 + 18 + bin)*256 + e] = m + cb2[e];
                }
            }
        } else if (blk < 256){            // ---- scale 1
            int r = blk - 96, b = r / 5, p = r % 5;
            int binA = 2*p;
            bool hasB = (2*p + 1 <= 8);
            int binB = hasB ? 2*p + 1 : binA;
            int bin = ((w >> 1) & 1) ? binB : binA;
            conv_sub<512, 24, 8>(x1, wt1, bsm0, bsm1, b, bin, w & 1, ntb, rmax);
#pragma unroll
            for (int i = 0; i < 4; ++i){
                float m = fmaxf(rmax[i], __shfl_xor(rmax[i], 32));
                if (hi == 0) red[w][i][lo] = m;
            }
            __syncthreads();
            int t = threadIdx.x;
            int binIdx = t >> 8, e = t & 255;
            int half = e >> 7, ntl = (e >> 5) & 3, l = e & 31;
            int w0 = half*4 + binIdx*2;
            float m = fmaxf(red[w0][ntl][l], red[w0+1][ntl][l]);
            if (binIdx == 0)      xc[((size_t)b*27 + 9 + binA)*256 + e] = m + cb1[e];
            else if (hasB)        xc[((size_t)b*27 + 9 + binB)*256 + e] = m + cb1[e];
        } else {                          // ---- scale 0
            int r = blk - 256, b = r / 9, bin = r % 9;
            int s0i = w & 3;
            conv_sub<256, 48, 16>(x0, wt0, bsm0, bsm1, b, bin, s0i,     ntb, rmax);
            conv_sub<256, 48, 16>(x0, wt0, bsm0, bsm1, b, bin, s0i + 4, ntb, rmax);
#pragma unroll
            for (int i = 0; i < 4; ++i){
                float m = fmaxf(rmax[i], __shfl_xor(rmax[i], 32));
                if (hi == 0) red[w][i][lo] = m;
            }
            __syncthreads();
            int t = threadIdx.x;
            if (t < 256){
                int e = t, half = e >> 7, ntl = (e >> 5) & 3, l = e & 31;
                int wb = half * 4;
                float m = fmaxf(fmaxf(red[wb][ntl][l], red[wb+1][ntl][l]),
                                fmaxf(red[wb+2][ntl][l], red[wb+3][ntl][l]));
                xc[((size_t)b*27 + bin)*256 + e] = m + cb0[e];
            }
        }
    } else {                              // ================= LN(text) + q-GEMM =================
        unsigned short* alds = (unsigned short*)smem;     // [32][520]
        size_t row0 = (size_t)(blk - 544) * 32;
        const float* gp = qg  + lane * 8;
        const float* bp = qbb + lane * 8;
        f32x4 g0 = *(const f32x4*)gp, g1 = *(const f32x4*)(gp+4);
        f32x4 b0 = *(const f32x4*)bp, b1 = *(const f32x4*)(bp+4);
#pragma unroll
        for (int it = 0; it < 4; ++it){
            int r = it * 8 + w;
            const float* p = text + (row0 + r) * 512 + lane * 8;
            f32x4 a = *(const f32x4*)p;
            f32x4 c = *(const f32x4*)(p + 4);
            float s = a[0]+a[1]+a[2]+a[3]+c[0]+c[1]+c[2]+c[3];
#pragma unroll
            for (int off = 32; off; off >>= 1) s += __shfl_xor(s, off);
            float mean = s * (1.f/512.f);
            float d[8];
            d[0]=a[0]-mean; d[1]=a[1]-mean; d[2]=a[2]-mean; d[3]=a[3]-mean;
            d[4]=c[0]-mean; d[5]=c[1]-mean; d[6]=c[2]-mean; d[7]=c[3]-mean;
            float vs = d[0]*d[0]+d[1]*d[1]+d[2]*d[2]+d[3]*d[3]+d[4]*d[4]+d[5]*d[5]+d[6]*d[6]+d[7]*d[7];
#pragma unroll
            for (int off = 32; off; off >>= 1) vs += __shfl_xor(vs, off);
            float rstd = rsqrtf(vs * (1.f/512.f) + 1e-5f);
            us8 o;
#pragma unroll
            for (int j = 0; j < 4; ++j) o[j]   = f2b(d[j]  *rstd*g0[j] + b0[j]);
#pragma unroll
            for (int j = 0; j < 4; ++j) o[4+j] = f2b(d[4+j]*rstd*g1[j] + b1[j]);
            *(us8*)(alds + (size_t)r * 520 + lane * 8) = o;
        }
        __syncthreads();

        f32x16 acc = zero16();
        const unsigned short* wf = qwt + (size_t)lane * 8;
        int nt = w;
        for (int ks = 0; ks < 32; ++ks){
            bf16x8 a = ld_bf16x8(alds + (size_t)lo * 520 + ks*16 + hi*8);
            bf16x8 bfr = ld_bf16x8(wf + (size_t)(ks*8 + nt) * 512);
            acc = mfma_bf16(a, bfr, acc);
        }
        int e = nt * 32 + lo;
        float qbias = qb[e];
#pragma unroll
        for (int r = 0; r < 16; ++r){
            size_t row = row0 + (r & 3) + 8 * (r >> 2) + 4 * hi;
            qout[row * 256 + e] = f2b(acc[r] + qbias);
        }
    }
}

// ---------------- fused LN(xc) + K/V GEMM (MFMA) ----------------
__global__ __launch_bounds__(256) void k_kv(const float* __restrict__ xc,
        const float* __restrict__ kg, const float* __restrict__ kb,
        const float* __restrict__ vg, const float* __restrict__ vb,
        const unsigned short* __restrict__ kwt, const unsigned short* __restrict__ vwt,
        const float* __restrict__ k_bias, const float* __restrict__ v_bias,
        float* __restrict__ kout, float* __restrict__ vout){
    __shared__ unsigned short lnk[32][264];
    __shared__ unsigned short lnv[32][264];
    int w = threadIdx.x >> 6, lane = threadIdx.x & 63, lo = lane & 31, hi = lane >> 5;
    size_t row0 = (size_t)blockIdx.x * 32;
    int c0 = lane * 4;
    f32x4 kgv = *(const f32x4*)(kg + c0), kbv = *(const f32x4*)(kb + c0);
    f32x4 vgv = *(const f32x4*)(vg + c0), vbv = *(const f32x4*)(vb + c0);
#pragma unroll
    for (int rr = 0; rr < 8; ++rr){
        int r = w * 8 + rr;
        f32x4 xv = *(const f32x4*)(xc + (row0 + r) * 256 + c0);
        float s = xv[0]+xv[1]+xv[2]+xv[3];
#pragma unroll
        for (int off = 32; off; off >>= 1) s += __shfl_xor(s, off);
        float mean = s * (1.f/256.f);
        float d0 = xv[0]-mean, d1 = xv[1]-mean, d2 = xv[2]-mean, d3 = xv[3]-mean;
        float vs = d0*d0 + d1*d1 + d2*d2 + d3*d3;
#pragma unroll
        for (int off = 32; off; off >>= 1) vs += __shfl_xor(vs, off);
        float rstd = rsqrtf(vs * (1.f/256.f) + 1e-5f);
        us4 uk, uv;
        uk[0] = f2b(d0*rstd*kgv[0] + kbv[0]); uv[0] = f2b(d0*rstd*vgv[0] + vbv[0]);
        uk[1] = f2b(d1*rstd*kgv[1] + kbv[1]); uv[1] = f2b(d1*rstd*vgv[1] + vbv[1]);
        uk[2] = f2b(d2*rstd*kgv[2] + kbv[2]); uv[2] = f2b(d2*rstd*vgv[2] + vbv[2]);
        uk[3] = f2b(d3*rstd*kgv[3] + kbv[3]); uv[3] = f2b(d3*rstd*vgv[3] + vbv[3]);
        *(us4*)(&lnk[r][c0]) = uk;
        *(us4*)(&lnv[r][c0]) = uv;
    }
    __syncthreads();

    f32x16 acc[4];
#pragma unroll
    for (int i = 0; i < 4; ++i) acc[i] = zero16();
    const unsigned short* lds = (w < 2) ? &lnk[0][0] : &lnv[0][0];
    const unsigned short* wf  = ((w < 2) ? kwt : vwt) + (size_t)lane * 8;
    int ntb = (w & 1) * 4;
    for (int ks = 0; ks < 16; ++ks){
        bf16x8 a = ld_bf16x8(lds + lo*264 + ks*16 + hi*8);
#pragma unroll
        for (int i = 0; i < 4; ++i){
            int nt = ntb + i;
            bf16x8 bfr = ld_bf16x8(wf + (size_t)(ks*8 + nt) * 512);
            acc[i] = mfma_bf16(a, bfr, acc[i]);
        }
    }
    const float* bias = (w < 2) ? k_bias : v_bias;
    float* outp = (w < 2) ? kout : vout;
#pragma unroll
    for (int i = 0; i < 4; ++i){
        int e = (ntb + i) * 32 + lo;
        float bv = bias[e];
#pragma unroll
        for (int r = 0; r < 16; ++r){
            size_t row = row0 + (r & 3) + 8 * (r >> 2) + 4 * hi;
            outp[row * 256 + e] = acc[i][r] + bv;
        }
    }
}

// ---------------- fused MFMA attention + out-proj (+bias +text residual) ----------------
__global__ __launch_bounds__(256, 3) void k_attnproj(const unsigned short* __restrict__ qbf,
        const float* __restrict__ kbuf, const float* __restrict__ vbuf,
        const unsigned short* __restrict__ pwt, const float* __restrict__ pb,
        const float* __restrict__ text, float* __restrict__ out){
    int b = blockIdx.x >> 4;
    int rg = blockIdx.x & 15;
    __shared__ unsigned short klds[32][264];
    __shared__ unsigned short vT[256][36];
    __shared__ unsigned short qolds[32][264];
    int tid = threadIdx.x;
    int w = tid >> 6, lane = tid & 63, lo = lane & 31, hi = lane >> 5;
    size_t grow0 = (size_t)b * 512 + rg * 32;

    // ---- stage K (bf16, rows 27..31 zero), V^T (bf16, k 27..35 zero), Q ----
    for (int i = tid; i < 27 * 64; i += 256){
        int row = i >> 6, c4 = (i & 63) << 2;
        f32x4 kv = *(const f32x4*)(kbuf + ((size_t)b*27 + row) * 256 + c4);
        us4 u; u[0]=f2b(kv[0]); u[1]=f2b(kv[1]); u[2]=f2b(kv[2]); u[3]=f2b(kv[3]);
        *(us4*)(&klds[row][c4]) = u;
    }
    for (int i = tid; i < 330; i += 256){
        int row = 27 + i / 66, c4 = (i % 66) * 4;
        us4 z = {0,0,0,0};
        *(us4*)(&klds[row][c4]) = z;
    }
    {
        int ch = tid;
        for (int k = 0; k < 27; ++k)
            vT[ch][k] = f2b(vbuf[((size_t)b*27 + k) * 256 + ch]);
#pragma unroll
        for (int k = 27; k < 36; ++k) vT[ch][k] = 0;
    }
    for (int i = tid; i < 1024; i += 256){
        int row = i >> 5, c8 = (i & 31) << 3;
        *(us8*)(&qolds[row][c8]) = *(const us8*)(qbf + (grow0 + row) * 256 + c8);
    }
    __syncthreads();

    // ---- attention: wave w handles heads w and w+4 ----
#pragma unroll
    for (int hh = 0; hh < 2; ++hh){
        int h = w + hh * 4;
        int hc = h * 32;
        f32x16 s = zero16();
        {
            bf16x8 A0 = ld_bf16x8(&klds[lo][hc + hi*8]);
            bf16x8 B0 = ld_bf16x8(&qolds[lo][hc + hi*8]);
            s = mfma_bf16(A0, B0, s);
            bf16x8 A1 = ld_bf16x8(&klds[lo][hc + 16 + hi*8]);
            bf16x8 B1 = ld_bf16x8(&qolds[lo][hc + 16 + hi*8]);
            s = mfma_bf16(A1, B1, s);
        }
        // per-lane softmax over k-regs (masked), + 1 shfl for partner half
        float mx = -3.4e38f;
#pragma unroll
        for (int r = 0; r < 16; ++r){
            bool valid = hi ? (r < 12) : (r != 15);
            if (valid) mx = fmaxf(mx, s[r]);
        }
        mx = fmaxf(mx, __shfl_xor(mx, 32));
        float p[16]; float sum = 0.f;
#pragma unroll
        for (int r = 0; r < 16; ++r){
            bool valid = hi ? (r < 12) : (r != 15);
            p[r] = valid ? __expf((s[r] - mx) * 0.17677669529663687f) : 0.f;
            sum += p[r];
        }
        sum += __shfl_xor(sum, 32);
        float inv = 1.f / sum;
        unsigned pd[8];
#pragma unroll
        for (int i = 0; i < 8; ++i)
            pd[i] = (unsigned)f2b(p[2*i]*inv) | ((unsigned)f2b(p[2*i+1]*inv) << 16);

        // PV: O^T = V^T . P  (2 k-steps; P-frag from regs + partner exchange)
        f32x16 o = zero16();
#pragma unroll
        for (int c = 0; c < 2; ++c){
            unsigned own0 = hi ? pd[4*c+2] : pd[4*c];
            unsigned own1 = hi ? pd[4*c+3] : pd[4*c+1];
            unsigned snd0 = hi ? pd[4*c]   : pd[4*c+2];
            unsigned snd1 = hi ? pd[4*c+1] : pd[4*c+3];
            unsigned rcv0 = (unsigned)__shfl_xor((int)snd0, 32);
            unsigned rcv1 = (unsigned)__shfl_xor((int)snd1, 32);
            u32x4 bd;
            bd[0] = hi ? rcv0 : own0;
            bd[1] = hi ? rcv1 : own1;
            bd[2] = hi ? own0 : rcv0;
            bd[3] = hi ? own1 : rcv1;
            bf16x8 B = __builtin_bit_cast(bf16x8, bd);
            bf16x8 A = ld_bf16x8(&vT[hc + lo][c*16 + hi*8]);
            o = mfma_bf16(A, B, o);
        }
        // write O to qolds: reg r -> ch = (r&3)+8*(r>>2)+4*hi
#pragma unroll
        for (int g = 0; g < 4; ++g){
            us4 u;
#pragma unroll
            for (int j = 0; j < 4; ++j) u[j] = f2b(o[g*4 + j]);
            *(us4*)(&qolds[lo][hc + g*8 + hi*4]) = u;
        }
    }
    __syncthreads();

    // ---- proj: out = O @ proj_w + proj_b + text ----
    f32x16 acc[4];
#pragma unroll
    for (int i = 0; i < 4; ++i) acc[i] = zero16();
    const unsigned short* wf = pwt + (size_t)lane * 8;
    for (int ks = 0; ks < 16; ++ks){
        bf16x8 a = ld_bf16x8(&qolds[lo][ks*16 + hi*8]);
#pragma unroll
        for (int i = 0; i < 4; ++i){
            int nt = w*4 + i;
            bf16x8 bfr = ld_bf16x8(wf + (size_t)(ks*16 + nt) * 512);
            acc[i] = mfma_bf16(a, bfr, acc[i]);
        }
    }
#pragma unroll
    for (int i = 0; i < 4; ++i){
        int ct = (w*4 + i) * 32 + lo;
        float pbias = pb[ct];
#pragma unroll
        for (int r = 0; r < 16; ++r){
            size_t row = grow0 + (r & 3) + 8 * (r >> 2) + 4 * hi;
            out[row * 512 + ct] = acc[i][r] + pbias + text[row * 512 + ct];
        }
    }
}

extern "C" void kernel_launch(void* const* d_in, const int* in_sizes, int n_in,
                              void* d_out, int out_size, void* d_ws, size_t ws_size,
                              hipStream_t stream) {
    (void)in_sizes; (void)n_in; (void)out_size; (void)ws_size;
    const float* x0     = (const float*)d_in[0];
    const float* x1     = (const float*)d_in[1];
    const float* x2     = (const float*)d_in[2];
    const float* text   = (const float*)d_in[3];
    const float* w0     = (const float*)d_in[4];
    const float* cb0    = (const float*)d_in[5];
    const float* w1     = (const float*)d_in[6];
    const float* cb1    = (const float*)d_in[7];
    const float* w2     = (const float*)d_in[8];
    const float* cb2    = (const float*)d_in[9];
    const float* q_ln_g = (const float*)d_in[10];
    const float* q_ln_b = (const float*)d_in[11];
    const float* k_ln_g = (const float*)d_in[12];
    const float* k_ln_b = (const float*)d_in[13];
    const float* v_ln_g = (const float*)d_in[14];
    const float* v_ln_b = (const float*)d_in[15];
    const float* q_w    = (const float*)d_in[16];
    const float* q_b    = (const float*)d_in[17];
    const float* k_w    = (const float*)d_in[18];
    const float* k_b    = (const float*)d_in[19];
    const float* v_w    = (const float*)d_in[20];
    const float* v_b    = (const float*)d_in[21];
    const float* proj_w = (const float*)d_in[22];
    const float* proj_b = (const float*)d_in[23];
    float* out = (float*)d_out;

    char* wsb = (char*)d_ws; size_t off = 0;
    auto take = [&](size_t bytes) -> void* {
        void* p = wsb + off; off += (bytes + 255) & ~(size_t)255; return p;
    };
    unsigned short* qbf    = (unsigned short*)take((size_t)16384 * 256 * 2);
    float*          xc     = (float*)take((size_t)32 * 27 * 256 * 4);
    float*          kbuf   = (float*)take((size_t)32 * 27 * 256 * 4);
    float*          vbuf   = (float*)take((size_t)32 * 27 * 256 * 4);
    unsigned short* wt0    = (unsigned short*)take((size_t)256 * 256 * 2);
    unsigned short* wt1    = (unsigned short*)take((size_t)256 * 512 * 2);
    unsigned short* wt2    = (unsigned short*)take((size_t)256 * 1024 * 2);
    unsigned short* qwt    = (unsigned short*)take((size_t)256 * 512 * 2);
    unsigned short* pwt    = (unsigned short*)take((size_t)512 * 256 * 2);
    unsigned short* kwt    = (unsigned short*)take((size_t)256 * 256 * 2);
    unsigned short* vwt    = (unsigned short*)take((size_t)256 * 256 * 2);

    k_prep<<<416, 256, 0, stream>>>(w0, w1, w2, q_w, proj_w, k_w, v_w,
                                    wt0, wt1, wt2, qwt, pwt, kwt, vwt);
    k_convlnq<<<1056, 512, 0, stream>>>(x0, x1, x2, wt0, wt1, wt2, cb0, cb1, cb2, xc,
                                        text, q_ln_g, q_ln_b, qwt, q_b, qbf);
    k_kv<<<27, 256, 0, stream>>>(xc, k_ln_g, k_ln_b, v_ln_g, v_ln_b,
                                 kwt, vwt, k_b, v_b, kbuf, vbuf);
    k_attnproj<<<512, 256, 0, stream>>>(qbf, kbuf, vbuf, pwt, proj_b, text, out);
}